// Round 9
// baseline (1045.623 us; speedup 1.0000x reference)
//
#include <hip/hip_runtime.h>

// Res_GN: recurrent GraphNet, T=4 x 2 layers, N=20000, E=320000.
// Runtime dtype dispatch (fp32/bf16 probed from coeff). bf16 hidden states,
// MFMA 16x16x32 bf16, fp32 accumulation, CSR gather for segment sums.
// R9: MFMA operand swap (D=[of][edge]) -> 8B/16B coalesced epilogue stores in
// edge/node/decoder; aggregate unrolled to 8 loads in flight.

typedef __attribute__((ext_vector_type(8))) short s16x8;
typedef __attribute__((ext_vector_type(4))) float f32x4;

#define T_STEPS 4
#define NN 20000
#define NP 20224   // NN padded to 256*79
#define NE 320000

__device__ __forceinline__ float bf2f(unsigned short h){
  return __uint_as_float(((unsigned)h)<<16);
}
__device__ __forceinline__ unsigned short f2bf(float f){
  unsigned u = __float_as_uint(f);
  return (unsigned short)((u + 0x7fffu + ((u>>16)&1u)) >> 16); // RNE
}
__device__ __forceinline__ float loadIn(const void* p, size_t i, int bf){
  return bf ? bf2f(((const unsigned short*)p)[i]) : ((const float*)p)[i];
}
__device__ __forceinline__ void storeOut(void* o, size_t i, float v, int bf){
  if(bf) ((unsigned short*)o)[i] = f2bf(v);
  else   ((float*)o)[i] = v;
}
__device__ __forceinline__ void load8(const float* __restrict__ p, float* v){
  const float4* q4 = (const float4*)p;
  float4 a = q4[0], b = q4[1];
  v[0]=a.x; v[1]=a.y; v[2]=a.z; v[3]=a.w;
  v[4]=b.x; v[5]=b.y; v[6]=b.z; v[7]=b.w;
}
__device__ __forceinline__ int4 pack8(const float* v){
  unsigned p0 = (unsigned)f2bf(v[0]) | ((unsigned)f2bf(v[1])<<16);
  unsigned p1 = (unsigned)f2bf(v[2]) | ((unsigned)f2bf(v[3])<<16);
  unsigned p2 = (unsigned)f2bf(v[4]) | ((unsigned)f2bf(v[5])<<16);
  unsigned p3 = (unsigned)f2bf(v[6]) | ((unsigned)f2bf(v[7])<<16);
  return make_int4((int)p0,(int)p1,(int)p2,(int)p3);
}
__device__ __forceinline__ int2 pack4(const float* v){
  unsigned u0 = (unsigned)f2bf(v[0]) | ((unsigned)f2bf(v[1])<<16);
  unsigned u1 = (unsigned)f2bf(v[2]) | ((unsigned)f2bf(v[3])<<16);
  return make_int2((int)u0,(int)u1);
}
__device__ __forceinline__ void unp4(int2 w, float* a){
  unsigned x;
  x=(unsigned)w.x; a[0]=__uint_as_float(x<<16); a[1]=__uint_as_float(x&0xffff0000u);
  x=(unsigned)w.y; a[2]=__uint_as_float(x<<16); a[3]=__uint_as_float(x&0xffff0000u);
}
__device__ __forceinline__ void unp8(int4 w, float* a){
  unsigned x;
  x=(unsigned)w.x; a[0]=__uint_as_float(x<<16); a[1]=__uint_as_float(x&0xffff0000u);
  x=(unsigned)w.y; a[2]=__uint_as_float(x<<16); a[3]=__uint_as_float(x&0xffff0000u);
  x=(unsigned)w.z; a[4]=__uint_as_float(x<<16); a[5]=__uint_as_float(x&0xffff0000u);
  x=(unsigned)w.w; a[6]=__uint_as_float(x<<16); a[7]=__uint_as_float(x&0xffff0000u);
}

union I4S8 { int4 i; s16x8 s; };

// ---------------- dtype probe ----------------
__global__ void probe_kernel(const void* coeff_in, int* flagp, float* coeff_f){
  unsigned short u = ((const unsigned short*)coeff_in)[0];
  float as_bf = bf2f(u);
  int f = (fabsf(as_bf - 0.1f) < 0.02f) ? 1 : 0;
  *flagp = f;
  *coeff_f = f ? as_bf : ((const float*)coeff_in)[0];
}

// ---------------- conv + zero (fused) ----------------
struct ConvJob { const void* src; float* dst; int n; };
struct ConvJobs { ConvJob j[16]; int cnt; };

__global__ void conv_kernel(ConvJobs jobs, const int* flagp, float* z, int zn){
  int bf = *flagp;
  int tid = blockIdx.x*blockDim.x + threadIdx.x;
  int stride = gridDim.x*blockDim.x;
  for(int q=0;q<jobs.cnt;q++){
    const void* s = jobs.j[q].src; float* d = jobs.j[q].dst; int n = jobs.j[q].n;
    for(int i=tid;i<n;i+=stride) d[i] = loadIn(s, i, bf);
  }
  for(int i=tid;i<zn;i+=stride) z[i]=0.f;
}

// ---------------- CSR build (one-time) ----------------
__global__ void csr_hist(const int* __restrict__ ei, int* deg_s, int* deg_r,
                         unsigned short* __restrict__ rank_s,
                         unsigned short* __restrict__ rank_r){
  int e = blockIdx.x*256+threadIdx.x;
  rank_s[e] = (unsigned short)atomicAdd(&deg_s[ei[e]],1);
  rank_r[e] = (unsigned short)atomicAdd(&deg_r[ei[NE+e]],1);
}

__global__ void csr_scan(const int* __restrict__ deg_s, int* __restrict__ off_s,
                         const int* __restrict__ deg_r, int* __restrict__ off_r){
  const int CH = NP/256;  // 79
  const int* deg = blockIdx.x ? deg_r : deg_s;
  int* off = blockIdx.x ? off_r : off_s;
  int t = threadIdx.x;
  int base = t*CH;
  int s = 0;
  #pragma unroll 8
  for(int i=0;i<CH;i++) s += deg[base+i];
  int lane = t & 63, w = t >> 6;
  int x = s;
  #pragma unroll
  for(int o=1;o<64;o<<=1){
    int y = __shfl_up(x, o, 64);
    if(lane >= o) x += y;
  }
  __shared__ int wtot[4];
  if(lane==63) wtot[w] = x;
  __syncthreads();
  int wbase = 0;
  #pragma unroll
  for(int k=0;k<3;k++) if(k<w) wbase += wtot[k];
  int acc = wbase + x - s;
  #pragma unroll 8
  for(int i=0;i<CH;i++){
    off[base+i]=acc; acc+=deg[base+i];
  }
  if(t==255) off[NN]=acc;
}

__global__ void csr_fill(const int* __restrict__ ei,
                         const int* __restrict__ s_off, const int* __restrict__ r_off,
                         const unsigned short* __restrict__ rank_s,
                         const unsigned short* __restrict__ rank_r,
                         int* __restrict__ csr_s, int* __restrict__ csr_r,
                         int2* __restrict__ sr2){
  int e = blockIdx.x*256+threadIdx.x;
  int s = ei[e], r = ei[NE+e];
  sr2[e] = make_int2(s,r);
  csr_s[s_off[s]+rank_s[e]] = e;
  csr_r[r_off[r]+rank_r[e]] = e;
}

// Pack weight [K=KW*32][NT*16] (row-major) into MFMA fragment order
// (same layout serves as A-frag for W^T or B-frag for W)
__global__ void pack_w_kernel(const void* __restrict__ W,
                              unsigned short* __restrict__ P, int KW, int NT,
                              const int* flagp){
  int bf = *flagp;
  int idx = blockIdx.x*blockDim.x + threadIdx.x;
  int total = NT*KW*512;
  if(idx>=total) return;
  int j = idx & 7;
  int lane = (idx>>3) & 63;
  int rest = idx >> 9;
  int kw = rest % KW;
  int nt = rest / KW;
  int k = kw*32 + (lane>>4)*8 + j;
  int n = nt*16 + (lane&15);
  P[idx] = f2bf(loadIn(W, (size_t)k*(NT*16) + n, bf));
}

// x_enc = relu(node_attr @ W_ne + b_ne)
__global__ void node_enc_kernel(const void* __restrict__ na,
                                const float* __restrict__ W, const float* __restrict__ b,
                                unsigned short* __restrict__ xA, const int* flagp){
  __shared__ float arow[4][12];
  int bf = *flagp;
  int lane = threadIdx.x & 63, nl = threadIdx.x >> 6;
  int row = blockIdx.x*4 + nl;
  if(lane<12) arow[nl][lane] = loadIn(na, (size_t)row*12+lane, bf);
  __syncthreads();
  float acc = b[lane];
  #pragma unroll
  for(int k=0;k<12;k++) acc += arow[nl][k]*W[k*64+lane];
  xA[(size_t)row*64+lane] = f2bf(fmaxf(acc,0.f));
}

// ---------------- edge block (MFMA, D=[of][edge], coalesced stores) --------
__global__ __launch_bounds__(256) void edge_block_mfma(
  const int2* __restrict__ sr2,
  const unsigned short* __restrict__ x_in,     // [N,64] bf16
  const unsigned short* __restrict__ h_x,      // [N,64] bf16 or null
  const void* __restrict__ e_attr,             // layer1 input base, else null
  int e_attr_off,
  const unsigned short* __restrict__ e_in,     // layer2: eBuf[t] bf16, else null
  const unsigned short* __restrict__ h_e,      // eBuf[t-1] bf16 or null
  const float* __restrict__ g,                 // [64] fp32
  const float* __restrict__ W_ee, const float* __restrict__ b_ee,
  const unsigned short* __restrict__ Wp,       // packed frags [2][12][64][8]
  const float* __restrict__ b_eb,
  unsigned short* __restrict__ e_out,          // [E,32] bf16 (may alias e_in)
  float* __restrict__ partial_e,               // [64][32]
  const int* flagp)
{
  const int tid = threadIdx.x;
  const int lane = tid&63;
  const int q = lane>>4, m16 = lane&15;
  const int pair = blockIdx.x*4 + (tid>>6);    // 10000 pairs, grid 2500 exact
  const int e0 = pair*32;
  const int eg0 = e0 + m16, eg1 = e0 + 16 + m16;
  const int2 sr0 = sr2[eg0], sr1 = sr2[eg1];
  const int o8 = q*8;
  const int4 z4 = make_int4(0,0,0,0);

  // cat fragments (B operand): lane holds features [8q,8q+8) of edge m16
  I4S8 A0[12], A1[12];
  if(e_attr){
    int bf = *flagp;
    float a0v = loadIn(e_attr, (size_t)e_attr_off + eg0, bf);
    float a1v = loadIn(e_attr, (size_t)e_attr_off + eg1, bf);
    float v[8];
    #pragma unroll
    for(int j=0;j<8;j++) v[j] = fmaxf(a0v*W_ee[o8+j]+b_ee[o8+j], 0.f);
    A0[0].i = pack8(v);
    #pragma unroll
    for(int j=0;j<8;j++) v[j] = fmaxf(a1v*W_ee[o8+j]+b_ee[o8+j], 0.f);
    A1[0].i = pack8(v);
  } else {
    A0[0].i = ((const int4*)(e_in + (size_t)eg0*32))[q];
    A1[0].i = ((const int4*)(e_in + (size_t)eg1*32))[q];
  }
  A0[1].i = h_e ? ((const int4*)(h_e + (size_t)eg0*32))[q] : z4;
  A1[1].i = h_e ? ((const int4*)(h_e + (size_t)eg1*32))[q] : z4;
  { const int4* p0 = (const int4*)(x_in + (size_t)sr0.x*64);
    const int4* p1 = (const int4*)(x_in + (size_t)sr1.x*64);
    A0[2].i = p0[q]; A1[2].i = p1[q];
    A0[3].i = p0[4+q]; A1[3].i = p1[4+q]; }
  if(h_x){
    const int4* p0 = (const int4*)(h_x + (size_t)sr0.x*64);
    const int4* p1 = (const int4*)(h_x + (size_t)sr1.x*64);
    A0[4].i = p0[q]; A1[4].i = p1[q];
    A0[5].i = p0[4+q]; A1[5].i = p1[4+q];
  } else { A0[4].i=z4; A1[4].i=z4; A0[5].i=z4; A1[5].i=z4; }
  { const int4* p0 = (const int4*)(x_in + (size_t)sr0.y*64);
    const int4* p1 = (const int4*)(x_in + (size_t)sr1.y*64);
    A0[6].i = p0[q]; A1[6].i = p1[q];
    A0[7].i = p0[4+q]; A1[7].i = p1[4+q]; }
  if(h_x){
    const int4* p0 = (const int4*)(h_x + (size_t)sr0.y*64);
    const int4* p1 = (const int4*)(h_x + (size_t)sr1.y*64);
    A0[8].i = p0[q]; A1[8].i = p1[q];
    A0[9].i = p0[4+q]; A1[9].i = p1[4+q];
  } else { A0[8].i=z4; A1[8].i=z4; A0[9].i=z4; A1[9].i=z4; }
  { float v[8];
    load8(g + o8, v);      A0[10].i = pack8(v); A1[10].i = A0[10].i;
    load8(g + 32 + o8, v); A0[11].i = pack8(v); A1[11].i = A0[11].i; }

  // D = W^T * cat^T : row = out-feature (q*4+r), col = edge (m16)
  f32x4 a00={0.f,0.f,0.f,0.f}, a01={0.f,0.f,0.f,0.f};
  f32x4 a10={0.f,0.f,0.f,0.f}, a11={0.f,0.f,0.f,0.f};
  #pragma unroll
  for(int kw=0;kw<12;kw++){
    s16x8 b0 = *(const s16x8*)(Wp + (size_t)(kw*64 + lane)*8);
    s16x8 b1 = *(const s16x8*)(Wp + (size_t)((12+kw)*64 + lane)*8);
    a00 = __builtin_amdgcn_mfma_f32_16x16x32_bf16(b0, A0[kw].s, a00, 0,0,0);
    a01 = __builtin_amdgcn_mfma_f32_16x16x32_bf16(b1, A0[kw].s, a01, 0,0,0);
    a10 = __builtin_amdgcn_mfma_f32_16x16x32_bf16(b0, A1[kw].s, a10, 0,0,0);
    a11 = __builtin_amdgcn_mfma_f32_16x16x32_bf16(b1, A1[kw].s, a11, 0,0,0);
  }

  const float4 bb0 = *(const float4*)(b_eb + q*4);
  const float4 bb1 = *(const float4*)(b_eb + 16 + q*4);
  float v00[4], v01[4], v10[4], v11[4], p0[4], p1[4];
  #pragma unroll
  for(int r=0;r<4;r++){
    float b0v = (&bb0.x)[r], b1v = (&bb1.x)[r];
    v00[r] = fmaxf(a00[r]+b0v, 0.f);
    v01[r] = fmaxf(a01[r]+b1v, 0.f);
    v10[r] = fmaxf(a10[r]+b0v, 0.f);
    v11[r] = fmaxf(a11[r]+b1v, 0.f);
    p0[r] = v00[r]+v10[r];
    p1[r] = v01[r]+v11[r];
  }
  *(int2*)(e_out + (size_t)eg0*32 + q*4)      = pack4(v00);
  *(int2*)(e_out + (size_t)eg0*32 + 16 + q*4) = pack4(v01);
  *(int2*)(e_out + (size_t)eg1*32 + q*4)      = pack4(v10);
  *(int2*)(e_out + (size_t)eg1*32 + 16 + q*4) = pack4(v11);

  // sum over edges: fold across m16 (lane bits 0..3)
  #pragma unroll
  for(int m=1;m<16;m<<=1){
    #pragma unroll
    for(int r=0;r<4;r++){
      p0[r] += __shfl_xor(p0[r], m, 64);
      p1[r] += __shfl_xor(p1[r], m, 64);
    }
  }
  if(m16==0){
    int slot = blockIdx.x & 63;
    #pragma unroll
    for(int r=0;r<4;r++){
      atomicAdd(&partial_e[slot*32 + q*4+r],      p0[r]);
      atomicAdd(&partial_e[slot*32 + 16 + q*4+r], p1[r]);
    }
  }
}

// ---------------- aggregate (8 edges in flight per wave) ----------------
__global__ void aggregate_kernel(const unsigned short* __restrict__ e_new,
  const int* __restrict__ s_off, const int* __restrict__ csr_s,
  const int* __restrict__ r_off, const int* __restrict__ csr_r,
  unsigned short* __restrict__ sentB, unsigned short* __restrict__ recvB)
{
  int node = blockIdx.x*4 + (threadIdx.x>>6);   // grid 5000 exact
  int lane = threadIdx.x & 63;
  int f = lane & 31, j = lane >> 5;
  float aS0=0.f, aS1=0.f, aS2=0.f, aS3=0.f;
  float aR0=0.f, aR1=0.f, aR2=0.f, aR3=0.f;
  {
    int end = s_off[node+1];
    int i = s_off[node] + j;
    for(; i+6<end; i+=8){
      aS0 += bf2f(e_new[(size_t)csr_s[i]*32 + f]);
      aS1 += bf2f(e_new[(size_t)csr_s[i+2]*32 + f]);
      aS2 += bf2f(e_new[(size_t)csr_s[i+4]*32 + f]);
      aS3 += bf2f(e_new[(size_t)csr_s[i+6]*32 + f]);
    }
    for(; i<end; i+=2)
      aS0 += bf2f(e_new[(size_t)csr_s[i]*32 + f]);
  }
  {
    int end = r_off[node+1];
    int i = r_off[node] + j;
    for(; i+6<end; i+=8){
      aR0 += bf2f(e_new[(size_t)csr_r[i]*32 + f]);
      aR1 += bf2f(e_new[(size_t)csr_r[i+2]*32 + f]);
      aR2 += bf2f(e_new[(size_t)csr_r[i+4]*32 + f]);
      aR3 += bf2f(e_new[(size_t)csr_r[i+6]*32 + f]);
    }
    for(; i<end; i+=2)
      aR0 += bf2f(e_new[(size_t)csr_r[i]*32 + f]);
  }
  float accS = (aS0+aS1)+(aS2+aS3), accR = (aR0+aR1)+(aR2+aR3);
  accS += __shfl_xor(accS,32,64);
  accR += __shfl_xor(accR,32,64);
  if(j==0){
    sentB[(size_t)node*32+f] = f2bf(accS);
    recvB[(size_t)node*32+f] = f2bf(accR);
  }
}

// ---------------- node block (dense MFMA, D=[of][node]) ----------------
__global__ __launch_bounds__(256) void node_block_mfma(
  const unsigned short* __restrict__ x_in, const unsigned short* __restrict__ h_x,
  const unsigned short* __restrict__ sentB, const unsigned short* __restrict__ recvB,
  const float* __restrict__ g,
  const unsigned short* __restrict__ Wp,       // packed [4][8][64][8]
  const float* __restrict__ b_nb,
  unsigned short* __restrict__ x_out, float* __restrict__ partial_x, // [64][64]
  void* __restrict__ out_base, size_t td_off, int has_td,
  const int* flagp)
{
  const int tid = threadIdx.x, lane = tid&63;
  const int q = lane>>4, m16 = lane&15;
  const int tile = blockIdx.x*4 + (tid>>6);
  if(tile >= NN/16) return;                    // grid 313, 1250 tiles
  const int n0 = tile*16;
  const int ng = n0+m16;
  const int o8 = q*8;
  const int4 z4 = make_int4(0,0,0,0);

  I4S8 A[8];
  { const int4* xp = (const int4*)(x_in + (size_t)ng*64);
    A[0].i = xp[q]; A[1].i = xp[4+q]; }
  if(h_x){ const int4* hp = (const int4*)(h_x + (size_t)ng*64);
    A[2].i = hp[q]; A[3].i = hp[4+q];
  } else { A[2].i = z4; A[3].i = z4; }
  A[4].i = ((const int4*)(sentB + (size_t)ng*32))[q];
  A[5].i = ((const int4*)(recvB + (size_t)ng*32))[q];
  { float v[8];
    load8(g + o8, v);      A[6].i = pack8(v);
    load8(g + 32 + o8, v); A[7].i = pack8(v); }

  f32x4 acc[4];
  #pragma unroll
  for(int nt=0;nt<4;nt++) acc[nt] = (f32x4){0.f,0.f,0.f,0.f};
  #pragma unroll
  for(int kw=0;kw<8;kw++){
    #pragma unroll
    for(int nt=0;nt<4;nt++){
      s16x8 b = *(const s16x8*)(Wp + (size_t)((nt*8+kw)*64 + lane)*8);
      acc[nt] = __builtin_amdgcn_mfma_f32_16x16x32_bf16(b, A[kw].s, acc[nt], 0,0,0);
    }
  }

  // D: row = of (nt*16+q*4+r), col = node (m16)
  int bf = has_td ? *flagp : 0;
  float ps[4][4];
  #pragma unroll
  for(int nt=0;nt<4;nt++){
    const float4 bb = *(const float4*)(b_nb + nt*16 + q*4);
    float v[4];
    #pragma unroll
    for(int r=0;r<4;r++) v[r] = fmaxf(acc[nt][r] + (&bb.x)[r], 0.f);
    *(int2*)(x_out + (size_t)ng*64 + nt*16 + q*4) = pack4(v);
    if(has_td){
      float hx[4] = {0.f,0.f,0.f,0.f};
      if(h_x) unp4(*(const int2*)(h_x + (size_t)ng*64 + nt*16 + q*4), hx);
      float td[4];
      #pragma unroll
      for(int r=0;r<4;r++) td[r] = v[r]-hx[r];
      size_t idx = td_off + (size_t)ng*64 + nt*16 + q*4;
      if(bf) *(int2*)((unsigned short*)out_base + idx) = pack4(td);
      else   *(float4*)((float*)out_base + idx) = make_float4(td[0],td[1],td[2],td[3]);
    }
    #pragma unroll
    for(int r=0;r<4;r++) ps[nt][r] = v[r];
  }
  // sum over nodes: fold across m16
  #pragma unroll
  for(int m=1;m<16;m<<=1){
    #pragma unroll
    for(int nt=0;nt<4;nt++)
      #pragma unroll
      for(int r=0;r<4;r++)
        ps[nt][r] += __shfl_xor(ps[nt][r], m, 64);
  }
  if(m16==0){
    int slot = blockIdx.x & 63;
    #pragma unroll
    for(int nt=0;nt<4;nt++)
      #pragma unroll
      for(int r=0;r<4;r++)
        atomicAdd(&partial_x[slot*64 + nt*16 + q*4 + r], ps[nt][r]);
  }
}

// ---------------- global block (256 thr, k-chunked; zeroes partials) --------
__global__ void global_block_kernel(float* __restrict__ partial_x,
  float* __restrict__ partial_e, const float* __restrict__ h_g,
  const float* __restrict__ W_gb, const float* __restrict__ b_gb,
  float* __restrict__ g_out)
{
  __shared__ float gcat[160];
  __shared__ float red[4][64];
  int tid = threadIdx.x;
  if(tid<64){
    float sx = 0.f;
    #pragma unroll 8
    for(int i=0;i<64;i++) sx += partial_x[i*64+tid];
    gcat[tid] = sx * (1.0f/(float)NN);
  } else if(tid<96){
    int j = tid-64;
    float se = 0.f;
    #pragma unroll 8
    for(int i=0;i<64;i++) se += partial_e[i*32+j];
    gcat[64+j] = se * (1.0f/(float)NE);
  } else if(tid<160){
    gcat[tid] = h_g[tid-96];
  }
  __syncthreads();
  int j = tid&63, c = tid>>6;
  float acc = 0.f;
  #pragma unroll 8
  for(int k=c*40;k<c*40+40;k++) acc += gcat[k]*W_gb[k*64+j];
  red[c][j] = acc;
  __syncthreads();
  for(int i=tid;i<2048;i+=256) partial_e[i]=0.f;
  for(int i=tid;i<4096;i+=256) partial_x[i]=0.f;
  if(tid<64){
    float a = red[0][tid]+red[1][tid]+red[2][tid]+red[3][tid] + b_gb[tid];
    g_out[tid] = fmaxf(a, 0.f);
  }
}

// ---------------- physics: spatial derivative (CSR gather, 4-way) ----------
__global__ void sder_csr_kernel(const int2* __restrict__ sr2,
  const void* __restrict__ spL, const unsigned short* __restrict__ x_new,
  const int* __restrict__ r_off, const int* __restrict__ csr_r,
  const float* __restrict__ coeff, void* __restrict__ out_base, size_t off,
  const int* flagp)
{
  int bf = *flagp;
  int lane = threadIdx.x&63, nl = threadIdx.x>>6;
  int node = blockIdx.x*4+nl;    // 5000 blocks exact
  float xn = bf2f(x_new[(size_t)node*64+lane]);
  float a0=0.f, a1=0.f, a2=0.f, a3=0.f;
  int beg = r_off[node], end = r_off[node+1];
  int i = beg;
  for(; i+4<=end; i+=4){
    int e1 = csr_r[i], e2 = csr_r[i+1], e3 = csr_r[i+2], e4 = csr_r[i+3];
    float w1 = loadIn(spL, e1, bf), w2 = loadIn(spL, e2, bf);
    float w3 = loadIn(spL, e3, bf), w4 = loadIn(spL, e4, bf);
    int s1 = sr2[e1].x, s2 = sr2[e2].x, s3 = sr2[e3].x, s4 = sr2[e4].x;
    a0 += w1*(bf2f(x_new[(size_t)s1*64+lane])-xn);
    a1 += w2*(bf2f(x_new[(size_t)s2*64+lane])-xn);
    a2 += w3*(bf2f(x_new[(size_t)s3*64+lane])-xn);
    a3 += w4*(bf2f(x_new[(size_t)s4*64+lane])-xn);
  }
  for(; i<end; i++){
    int e1 = csr_r[i];
    float w1 = loadIn(spL, e1, bf);
    a0 += w1*(bf2f(x_new[(size_t)sr2[e1].x*64+lane])-xn);
  }
  storeOut(out_base, off + (size_t)node*64+lane, coeff[0]*((a0+a1)+(a2+a3)), bf);
}

__global__ void add_bf16_kernel(const unsigned short* __restrict__ a,
  const unsigned short* __restrict__ b, unsigned short* __restrict__ c, int n){
  int i = blockIdx.x*blockDim.x+threadIdx.x;
  int stride = gridDim.x*blockDim.x;
  for(;i<n;i+=stride) c[i] = f2bf(bf2f(a[i])+bf2f(b[i]));
}

// ---------------- decoder (MFMA, D=[of][row]) ----------------
__global__ __launch_bounds__(256) void decoder_kernel(
  const unsigned short* __restrict__ xs, const unsigned short* __restrict__ xr,
  const unsigned short* __restrict__ WpD,   // packed [4][2][64][8]
  const float* __restrict__ b1, const float* __restrict__ W2,
  const float* __restrict__ b2,
  void* __restrict__ out_base, const int* flagp)
{
  const int tid=threadIdx.x, lane=tid&63;
  const int q=lane>>4, m16=lane&15;
  const int tile = blockIdx.x*4 + (tid>>6);   // 5000 tiles, grid 1250 exact
  const int row0 = tile*16;
  const int rg = row0 + m16;

  I4S8 A[2];
  #pragma unroll
  for(int kw=0;kw<2;kw++){
    int4 xa = ((const int4*)(xs + (size_t)rg*64 + kw*32))[q];
    int4 xb = ((const int4*)(xr + (size_t)rg*64 + kw*32))[q];
    float va[8], vb[8], v[8];
    unp8(xa, va); unp8(xb, vb);
    #pragma unroll
    for(int j=0;j<8;j++) v[j] = va[j]+vb[j];
    A[kw].i = pack8(v);
  }

  f32x4 acc[4];
  #pragma unroll
  for(int nt=0;nt<4;nt++) acc[nt] = (f32x4){0.f,0.f,0.f,0.f};
  #pragma unroll
  for(int kw=0;kw<2;kw++){
    #pragma unroll
    for(int nt=0;nt<4;nt++){
      s16x8 b = *(const s16x8*)(WpD + (size_t)((nt*2+kw)*64 + lane)*8);
      acc[nt] = __builtin_amdgcn_mfma_f32_16x16x32_bf16(b, A[kw].s, acc[nt], 0,0,0);
    }
  }

  // D: row = of (nt*16+q*4+r), col = graph-row (m16)
  float val = 0.f;
  #pragma unroll
  for(int nt=0;nt<4;nt++){
    const float4 bb = *(const float4*)(b1 + nt*16 + q*4);
    const float4 w2 = *(const float4*)(W2 + nt*16 + q*4);
    #pragma unroll
    for(int r=0;r<4;r++)
      val += fmaxf(acc[nt][r] + (&bb.x)[r], 0.f) * (&w2.x)[r];
  }
  val += __shfl_xor(val, 16, 64);
  val += __shfl_xor(val, 32, 64);
  if(q==0){
    storeOut(out_base, (size_t)rg, val + b2[0], *flagp);
  }
}

// ---------------- launch ----------------
extern "C" void kernel_launch(void* const* d_in, const int* in_sizes, int n_in,
                              void* d_out, int out_size, void* d_ws, size_t ws_size,
                              hipStream_t stream){
  const void* node_attr = d_in[0];
  const void* edge_attr = d_in[1];
  const int*  ei        = (const int*)d_in[2];
  const void* spL       = d_in[3];
  const void* gattr     = d_in[4];
  const void* coeff_in  = d_in[5];
  const void* W_ee_in = d_in[6];  const void* b_ee_in = d_in[7];
  const void* W_ne_in = d_in[8];  const void* b_ne_in = d_in[9];
  const void* W_eb_in = d_in[10]; const void* b_eb_in = d_in[11];
  const void* W_nb_in = d_in[12]; const void* b_nb_in = d_in[13];
  const void* W_gb_in = d_in[14]; const void* b_gb_in = d_in[15];
  const void* W_nd1_in= d_in[16]; const void* b_nd1_in= d_in[17];
  const void* W_nd2_in= d_in[18]; const void* b_nd2_in= d_in[19];

  // ---- workspace layout (~122 MB) ----
  float* ws = (float*)d_ws;
  float* W_ee_f = ws;             float* b_ee_f = W_ee_f+32;
  float* W_ne_f = b_ee_f+32;      float* b_ne_f = W_ne_f+768;
  float* W_gb_f = b_ne_f+64;      float* b_gb_f = W_gb_f+10240;
  float* W_nd1_f= b_gb_f+64;      float* b_nd1_f= W_nd1_f+4096;
  float* W_nd2_f= b_nd1_f+64;     float* b_nd2_f= W_nd2_f+64;
  float* b_eb_f = b_nd2_f+1;      float* b_nb_f = b_eb_f+32;
  float* coeff_f= b_nb_f+64;                        // idx 15522
  int*   flagp  = (int*)(ws + 15523);
  float* gbuf   = ws + 15524;                       // 9*64 slots
  float* part_e = ws + 16100;                       // 64*32
  float* part_x = part_e + 2048;                    // 64*64
  int*   deg_s  = (int*)(part_x + 4096);            // NP (padded)
  int*   deg_r  = deg_s + NP;                       // NP
  int*   s_off  = deg_r + NP;                       // NP+1
  int*   r_off  = s_off + NP+1;                     // NP+1
  unsigned short* rank_s = (unsigned short*)(r_off + NP+1); // NE ushort
  unsigned short* rank_r = rank_s + NE;                     // NE ushort
  int*   csr_s  = (int*)(rank_r + NE);              // E
  int*   csr_r  = csr_s + NE;                       // E
  size_t iend   = (size_t)((int*)(csr_r + NE) - (int*)ws);
  iend = (iend + 3) & ~(size_t)3;                   // 16B align
  int2*  sr2    = (int2*)(ws + iend);               // E int2
  unsigned short* sentB = (unsigned short*)(sr2 + NE);   // N*32 bf16
  unsigned short* recvB = sentB + (size_t)NN*32;         // N*32 bf16
  unsigned short* eBuf  = recvB + (size_t)NN*32;         // T*E*32 bf16
  unsigned short* xA    = eBuf + (size_t)T_STEPS*NE*32;
  unsigned short* xB    = xA + (size_t)T_STEPS*NN*64;
  unsigned short* xC    = xB + (size_t)T_STEPS*NN*64;
  unsigned short* WpE   = xC + (size_t)T_STEPS*NN*64; // 12288 ushort
  unsigned short* WpN   = WpE + 12288;                // 16384 ushort
  unsigned short* WpD   = WpN + 16384;                // 4096 ushort

  // 0) dtype probe
  probe_kernel<<<1,1,0,stream>>>(coeff_in, flagp, coeff_f);

  // 1) small fp32 conversions + zero partials/deg (incl. padding)
  ConvJobs jobs; int c=0;
  auto add=[&](const void* s, float* d, int n){ jobs.j[c].src=s; jobs.j[c].dst=d; jobs.j[c].n=n; c++; };
  add(W_ee_in,W_ee_f,32);   add(b_ee_in,b_ee_f,32);
  add(W_ne_in,W_ne_f,768);  add(b_ne_in,b_ne_f,64);
  add(W_gb_in,W_gb_f,10240);add(b_gb_in,b_gb_f,64);
  add(W_nd1_in,W_nd1_f,4096);add(b_nd1_in,b_nd1_f,64);
  add(W_nd2_in,W_nd2_f,64); add(b_nd2_in,b_nd2_f,1);
  add(b_eb_in,b_eb_f,32);   add(b_nb_in,b_nb_f,64);
  add(gattr,gbuf,64);
  jobs.cnt=c;
  conv_kernel<<<64,256,0,stream>>>(jobs, flagp, part_e, 2048+4096+2*NP);

  // 2) CSR build (hist records ranks; fill is atomic-free)
  csr_hist<<<NE/256,256,0,stream>>>(ei, deg_s, deg_r, rank_s, rank_r);
  csr_scan<<<2,256,0,stream>>>(deg_s, s_off, deg_r, r_off);
  csr_fill<<<NE/256,256,0,stream>>>(ei, s_off, r_off, rank_s, rank_r, csr_s, csr_r, sr2);

  // 3) pack MFMA weight fragments
  pack_w_kernel<<<48,256,0,stream>>>(W_eb_in, WpE, 12, 2, flagp);
  pack_w_kernel<<<64,256,0,stream>>>(W_nb_in, WpN, 8, 4, flagp);
  pack_w_kernel<<<16,256,0,stream>>>(W_nd1_in, WpD, 2, 4, flagp);

  // 4) node encoder -> xA (bf16)
  node_enc_kernel<<<T_STEPS*NN/4,256,0,stream>>>(node_attr, W_ne_f, b_ne_f, xA, flagp);

  const size_t td_base = (size_t)T_STEPS*NN;                 // 80000
  const size_t sd_base = td_base + (size_t)T_STEPS*NN*64;

  for(int layer=0; layer<2; layer++){
    for(int t=0;t<T_STEPS;t++){
      const unsigned short* x_in = (layer==0? xA : xC) + (size_t)t*NN*64;
      const unsigned short* h_x  = (t>0)? xB + (size_t)(t-1)*NN*64 : nullptr;
      const unsigned short* h_e  = (t>0)? eBuf + (size_t)(t-1)*NE*32 : nullptr;
      const float* gptr = (layer==0)? gbuf + t*64
                                    : (t==0? gbuf+1*64 : gbuf+(4+t)*64);
      float*       gout = (layer==0)? gbuf+(1+t)*64 : gbuf+(5+t)*64;
      const void*  eat  = (layer==0)? edge_attr : nullptr;
      const unsigned short* e_in = (layer==0)? nullptr : eBuf + (size_t)t*NE*32;
      unsigned short*       e_out= eBuf + (size_t)t*NE*32;

      edge_block_mfma<<<NE/128,256,0,stream>>>(sr2, x_in, h_x, eat, t*NE, e_in, h_e, gptr,
          W_ee_f, b_ee_f, WpE, b_eb_f, e_out, part_e, flagp);

      aggregate_kernel<<<NN/4,256,0,stream>>>(e_out, s_off, csr_s, r_off, csr_r,
          sentB, recvB);

      unsigned short* x_out = xB + (size_t)t*NN*64;
      size_t td_off = td_base + (size_t)t*NN*64;
      node_block_mfma<<<(NN/16+3)/4,256,0,stream>>>(x_in, h_x, sentB, recvB, gptr,
          WpN, b_nb_f, x_out, part_x, d_out, td_off, (layer==1)?1:0, flagp);

      global_block_kernel<<<1,256,0,stream>>>(part_x, part_e, gptr, W_gb_f, b_gb_f, gout);

      if(layer==1){
        sder_csr_kernel<<<NN/4,256,0,stream>>>(sr2, spL, x_out, r_off, csr_r,
            coeff_f, d_out, sd_base + (size_t)t*NN*64, flagp);
      }
    }
    if(layer==0){
      add_bf16_kernel<<<2048,256,0,stream>>>(xA, xB, xC, T_STEPS*NN*64);
    }
  }

  decoder_kernel<<<(T_STEPS*NN/16+3)/4,256,0,stream>>>(xB, xC, WpD,
      b_nd1_f, W_nd2_f, b_nd2_f, d_out, flagp);
}